// Round 7
// baseline (360.676 us; speedup 1.0000x reference)
//
#include <hip/hip_runtime.h>
#include <hip/hip_bf16.h>

typedef __attribute__((ext_vector_type(8))) short bf16x8;
typedef __attribute__((ext_vector_type(4))) short bf16x4;
typedef __attribute__((ext_vector_type(4))) float f32x4;

__device__ __forceinline__ short f2bf(float f){
  __hip_bfloat16 h = __float2bfloat16(f);
  return __builtin_bit_cast(short, h);
}
__device__ __forceinline__ float bf2f(short s){
  unsigned u = ((unsigned)(unsigned short)s) << 16;
  return __builtin_bit_cast(float, u);
}

__device__ __forceinline__ void gload_lds16(const short* g, char* l){
  __builtin_amdgcn_global_load_lds(
      (const __attribute__((address_space(1))) void*)g,
      (__attribute__((address_space(3))) void*)l, 16, 0, 0);
}

#define SB0() __builtin_amdgcn_sched_barrier(0)
#define BARRIER() do{ SB0(); __builtin_amdgcn_s_barrier(); }while(0)

// ---------------- GroupNorm stats ----------------
__global__ __launch_bounds__(256) void gn_stats(const float* __restrict__ x,
                                                float* __restrict__ stats){
  int b = blockIdx.x >> 5, g = blockIdx.x & 31;
  const float4* p = (const float4*)(x + ((long long)b*512 + g*16)*4096);
  float s = 0.f, s2 = 0.f;
  for (int i = threadIdx.x; i < 16384; i += 256){
    float4 v = p[i];
    s  += v.x + v.y + v.z + v.w;
    s2 += v.x*v.x + v.y*v.y + v.z*v.z + v.w*v.w;
  }
  #pragma unroll
  for (int o = 32; o; o >>= 1){ s += __shfl_xor(s, o); s2 += __shfl_xor(s2, o); }
  __shared__ float rs[4], rs2[4];
  int wid = threadIdx.x >> 6;
  if ((threadIdx.x & 63) == 0){ rs[wid] = s; rs2[wid] = s2; }
  __syncthreads();
  if (threadIdx.x == 0){
    float S  = rs[0]+rs[1]+rs[2]+rs[3];
    float S2 = rs2[0]+rs2[1]+rs2[2]+rs2[3];
    float mean = S * (1.f/65536.f);
    float var  = S2 * (1.f/65536.f) - mean*mean;
    stats[blockIdx.x*2]   = mean;
    stats[blockIdx.x*2+1] = rsqrtf(var + 1e-6f);
  }
}

// ------------- GN apply + transpose -> h bf16 [B,N,C] ------------------
__global__ __launch_bounds__(256) void gn_apply(const float* __restrict__ x,
                                                const float* __restrict__ stats,
                                                const float* __restrict__ gw,
                                                const float* __restrict__ gb,
                                                short* __restrict__ h){
  __shared__ float tile[128][65];
  int b  = blockIdx.y;
  int n0 = blockIdx.x * 64;
  int t  = threadIdx.x;
  const float* xb = x + (long long)b*512*4096;
  for (int cc = 0; cc < 4; cc++){
    int c0 = cc*128;
    #pragma unroll
    for (int r = 0; r < 128; r += 4){
      int c = r + (t >> 6);
      tile[c][t & 63] = xb[(long long)(c0+c)*4096 + n0 + (t & 63)];
    }
    __syncthreads();
    int n = t >> 2, cp = (t & 3)*32;
    short tmp[32];
    #pragma unroll
    for (int j = 0; j < 32; j++){
      int c = c0 + cp + j;
      float mean = stats[(b*32 + (c >> 4))*2];
      float rstd = stats[(b*32 + (c >> 4))*2 + 1];
      float v = (tile[cp+j][n] - mean)*rstd*gw[c] + gb[c];
      tmp[j] = f2bf(v);
    }
    long long ho = ((long long)b*4096 + n0 + n)*512 + c0 + cp;
    #pragma unroll
    for (int j2 = 0; j2 < 4; j2++){
      bf16x8 v8;
      #pragma unroll
      for (int e = 0; e < 8; e++) v8[e] = tmp[j2*8 + e];
      *(bf16x8*)&h[ho + j2*8] = v8;
    }
    __syncthreads();
  }
}

// ---------- fp32 -> bf16 weights ----------
__global__ __launch_bounds__(256) void f2bf_all(
    const float* __restrict__ w0, const float* __restrict__ w1,
    const float* __restrict__ w2, const float* __restrict__ w3,
    short* __restrict__ o0, short* __restrict__ o1,
    short* __restrict__ o2, short* __restrict__ o3){
  int idx = blockIdx.x*256 + threadIdx.x;
  int m = idx >> 15, r = idx & 32767;
  const float* src = (m==0) ? w0 : (m==1) ? w1 : (m==2) ? w2 : w3;
  short* dst       = (m==0) ? o0 : (m==1) ? o1 : (m==2) ? o2 : o3;
  const float4* p = (const float4*)src + (long long)r*2;
  float4 a = p[0], c = p[1];
  bf16x8 v;
  v[0]=f2bf(a.x); v[1]=f2bf(a.y); v[2]=f2bf(a.z); v[3]=f2bf(a.w);
  v[4]=f2bf(c.x); v[5]=f2bf(c.y); v[6]=f2bf(c.z); v[7]=f2bf(c.w);
  *(bf16x8*)&dst[(long long)r*8] = v;
}

// ---------------- row softmax in place ----------------
__global__ __launch_bounds__(256) void softmax_rows(short* __restrict__ S){
  long long row = blockIdx.x;
  short* p = S + row*4096;
  int t = threadIdx.x;
  bf16x8 v0 = *(bf16x8*)&p[t*16];
  bf16x8 v1 = *(bf16x8*)&p[t*16 + 8];
  float f[16];
  #pragma unroll
  for (int e = 0; e < 8; e++){ f[e] = bf2f(v0[e]); f[8+e] = bf2f(v1[e]); }
  float m = f[0];
  #pragma unroll
  for (int e = 1; e < 16; e++) m = fmaxf(m, f[e]);
  #pragma unroll
  for (int o = 32; o; o >>= 1) m = fmaxf(m, __shfl_xor(m, o));
  __shared__ float red[4];
  int wid = t >> 6;
  if ((t & 63) == 0) red[wid] = m;
  __syncthreads();
  m = fmaxf(fmaxf(red[0], red[1]), fmaxf(red[2], red[3]));
  float s = 0.f;
  #pragma unroll
  for (int e = 0; e < 16; e++){ f[e] = exp2f((f[e]-m)*1.4426950408889634f); s += f[e]; }
  #pragma unroll
  for (int o = 32; o; o >>= 1) s += __shfl_xor(s, o);
  __syncthreads();
  if ((t & 63) == 0) red[wid] = s;
  __syncthreads();
  s = red[0]+red[1]+red[2]+red[3];
  float inv = 1.f/s;
  #pragma unroll
  for (int e = 0; e < 8; e++){ v0[e] = f2bf(f[e]*inv); v1[e] = f2bf(f[8+e]*inv); }
  *(bf16x8*)&p[t*16]     = v0;
  *(bf16x8*)&p[t*16 + 8] = v1;
}

// ======= 256xBN bf16 GEMM, 8 waves, BK=64, 4-phase frag-ahead pipeline =======
// Per-wave 128x64 (BN=256) or 64x64 (BN=128). Fragments for phase q+1 are
// ds_read during phase q (alternating register sets); counted lgkm per phase.
// Stages: A(kt+1) at ph0/ph1 (into other buf), B(kt+2) at ph2/ph3 (into cur buf
// B region, free after ph0). One vmcnt(2) per K-tile at ph2.
// MODE 0: bf16 [M][Nn] swapped-operand; MODE 1: bf16 [Nn][M]; MODE 2: fp32
// [Nn][M] + residual.
template<int MODE, int BN, bool SWZ>
__global__ __launch_bounds__(512, 2) void gemmF(
    const short* __restrict__ A, const short* __restrict__ Bw,
    const float* __restrict__ bias,
    void* __restrict__ outp, const float* __restrict__ resid,
    int M, int Nn, int Kd,
    long long sA, long long sB, long long sO, float scale)
{
  constexpr int WARPS_N = BN/64;          // 4 or 2
  constexpr int WARPS_M = 8/WARPS_N;      // 2 or 4
  constexpr int WM = 256/WARPS_M;         // 128 or 64
  constexpr int MF = WM/16;               // 8 or 4
  constexpr int QR = MF/4;                // 2 or 1 rows per quadrant-phase
  constexpr int ABYT = 32768;             // A: 256x64 bf16
  constexpr int BBYT = BN*128;
  constexpr int BUFSZ = ABYT + BBYT;
  constexpr int BH = BBYT/16384;          // B half-tiles: 2 or 1
  extern __shared__ char smem[];

  int bx, by, bz;
  if constexpr (SWZ){
    // 1024 blocks: XCD owns 2 bx-strips; by inner for B-panel L2 reuse.
    int id = blockIdx.x;
    int xcd = id & 7, s = id >> 3;        // s 0..127
    int bxh = s >> 6, rem = s & 63;
    bx = xcd*2 + bxh; by = rem & 15; bz = rem >> 4;
  } else { bx = blockIdx.x; by = blockIdx.y; bz = blockIdx.z; }

  const short* Ab = A + bz*sA;
  const short* Bb = Bw + bz*sB;
  const int m0 = bx*256, n0 = by*BN;
  const int t = threadIdx.x;
  const int lane = t & 63, wid = t >> 6;
  const int g = lane >> 4, lr = lane & 15;
  const int wr = wid / WARPS_N, wc = wid % WARPS_N;
  const long long KdLL = Kd;

  const int r0 = t >> 3, c8 = t & 7;

  auto STAGE_A = [&](int kt, int buf, int h){
    char* d = smem + buf*BUFSZ + h*16384 + t*16;
    #pragma unroll
    for (int j = 0; j < 2; j++){
      int row = h*128 + j*64 + r0;
      gload_lds16(Ab + (long long)(m0+row)*KdLL + (long long)kt*64 + ((c8 ^ (row&7))*8),
                  d + j*8192);
    }
  };
  auto STAGE_B = [&](int kt, int buf, int h){
    char* d = smem + buf*BUFSZ + ABYT + h*16384 + t*16;
    #pragma unroll
    for (int j = 0; j < 2; j++){
      int row = h*128 + j*64 + r0;
      gload_lds16(Bb + (long long)(n0+row)*KdLL + (long long)kt*64 + ((c8 ^ (row&7))*8),
                  d + j*8192);
    }
  };

  int roA[MF], swA[MF], roB[4], swB[4];
  #pragma unroll
  for (int mf = 0; mf < MF; mf++){
    int ra = wr*WM + mf*16 + lr;
    roA[mf] = (ra>>7)*16384 + (ra&127)*128; swA[mf] = ra & 7;
  }
  #pragma unroll
  for (int nf = 0; nf < 4; nf++){
    int rb = wc*64 + nf*16 + lr;
    roB[nf] = ABYT + (rb>>7)*16384 + (rb&127)*128; swB[nf] = rb & 7;
  }

  f32x4 acc[MF][4];
  #pragma unroll
  for (int i = 0; i < MF; i++)
    #pragma unroll
    for (int j = 0; j < 4; j++)
      acc[i][j] = f32x4{0.f,0.f,0.f,0.f};
  bf16x8 av[2][QR][2], bv[4][2];

  #define RD_AV(SET, Q, BASE) do{                                         \
    _Pragma("unroll")                                                     \
    for (int _i = 0; _i < QR; _i++)                                       \
      _Pragma("unroll")                                                   \
      for (int _ks = 0; _ks < 2; _ks++){                                  \
        int _x = (Q)*QR + _i;                                             \
        av[SET][_i][_ks] = *(const bf16x8*)((BASE) + roA[_x] +            \
                            (((_ks*4+g) ^ swA[_x])<<4));                  \
      } }while(0)

  #define RD_BV(BASE) do{                                                 \
    _Pragma("unroll")                                                     \
    for (int _n = 0; _n < 4; _n++)                                        \
      _Pragma("unroll")                                                   \
      for (int _ks = 0; _ks < 2; _ks++)                                   \
        bv[_n][_ks] = *(const bf16x8*)((BASE) + roB[_n] +                 \
                            (((_ks*4+g) ^ swB[_n])<<4));                  \
    }while(0)

  #define MFMA_PH(Q, SET) do{                                             \
    __builtin_amdgcn_s_setprio(1);                                        \
    _Pragma("unroll")                                                     \
    for (int _ks = 0; _ks < 2; _ks++)                                     \
      _Pragma("unroll")                                                   \
      for (int _n = 0; _n < 4; _n++)                                      \
        _Pragma("unroll")                                                 \
        for (int _i = 0; _i < QR; _i++){                                  \
          if constexpr (MODE == 0)                                        \
            acc[(Q)*QR+_i][_n] = __builtin_amdgcn_mfma_f32_16x16x32_bf16( \
              bv[_n][_ks], av[SET][_i][_ks], acc[(Q)*QR+_i][_n], 0,0,0);  \
          else                                                            \
            acc[(Q)*QR+_i][_n] = __builtin_amdgcn_mfma_f32_16x16x32_bf16( \
              av[SET][_i][_ks], bv[_n][_ks], acc[(Q)*QR+_i][_n], 0,0,0);  \
        }                                                                 \
    __builtin_amdgcn_s_setprio(0); }while(0)

  #define WAIT_LGKM_JI() do{                                              \
    if constexpr (QR == 2) asm volatile("s_waitcnt lgkmcnt(4)":::"memory");\
    else                   asm volatile("s_waitcnt lgkmcnt(2)":::"memory");\
    SB0(); }while(0)

  const int NT = Kd >> 6;

  // prologue: A(0), B(0), B(1); leave B(1) in flight
  STAGE_A(0,0,0); STAGE_A(0,0,1);
  STAGE_B(0,0,0); if constexpr (BH==2) STAGE_B(0,0,1);
  STAGE_B(1,1,0); if constexpr (BH==2) STAGE_B(1,1,1);
  if constexpr (BH==2) asm volatile("s_waitcnt vmcnt(4)":::"memory");
  else                 asm volatile("s_waitcnt vmcnt(2)":::"memory");
  SB0();
  __builtin_amdgcn_s_barrier();
  RD_AV(0, 0, smem);                  // av0(tile0) -> set0

  for (int kt = 0; kt < NT; ++kt){
    char* bc  = smem + (kt & 1)*BUFSZ;
    char* bn_ = smem + ((kt & 1)^1)*BUFSZ;
    // ---- ph0: MFMA q0; read bv(kt)+av1; stage A0(kt+1)
    RD_BV(bc);
    RD_AV(1, 1, bc);
    if (kt+1 < NT) STAGE_A(kt+1, (kt&1)^1, 0);
    BARRIER();
    WAIT_LGKM_JI();
    MFMA_PH(0, 0);
    BARRIER();
    // ---- ph1: MFMA q1; read av2; stage A1(kt+1)
    RD_AV(0, 2, bc);
    if (kt+1 < NT) STAGE_A(kt+1, (kt&1)^1, 1);
    BARRIER();
    WAIT_LGKM_JI();
    MFMA_PH(1, 1);
    BARRIER();
    // ---- ph2: MFMA q2; read av3; stage B0(kt+2); vmcnt
    RD_AV(1, 3, bc);
    if (kt+2 < NT) STAGE_B(kt+2, kt&1, 0);
    BARRIER();
    if (kt+2 < NT) asm volatile("s_waitcnt vmcnt(2)":::"memory");
    else           asm volatile("s_waitcnt vmcnt(0)":::"memory");
    SB0();
    WAIT_LGKM_JI();
    MFMA_PH(2, 0);
    BARRIER();
    // ---- ph3: MFMA q3; read av0(kt+1); stage B1(kt+2)
    if (kt+1 < NT) RD_AV(0, 0, bn_);
    if constexpr (BH==2){ if (kt+2 < NT) STAGE_B(kt+2, kt&1, 1); }
    BARRIER();
    if (kt+1 < NT){ WAIT_LGKM_JI(); }
    else { asm volatile("s_waitcnt lgkmcnt(0)":::"memory"); SB0(); }
    MFMA_PH(3, 1);
    BARRIER();
  }

  if constexpr (MODE == 0){
    short* outb = (short*)outp + bz*sO;
    const bool hb = (bias != nullptr);
    #pragma unroll
    for (int mi = 0; mi < MF; mi++){
      int row = m0 + wr*WM + mi*16 + lr;
      #pragma unroll
      for (int ni = 0; ni < 4; ni++){
        int col = n0 + wc*64 + ni*16 + g*4;
        float b0=0.f,b1=0.f,b2=0.f,b3=0.f;
        if (hb){ float4 bb = *(const float4*)&bias[col]; b0=bb.x; b1=bb.y; b2=bb.z; b3=bb.w; }
        bf16x4 pk;
        pk[0] = f2bf((acc[mi][ni][0] + b0)*scale);
        pk[1] = f2bf((acc[mi][ni][1] + b1)*scale);
        pk[2] = f2bf((acc[mi][ni][2] + b2)*scale);
        pk[3] = f2bf((acc[mi][ni][3] + b3)*scale);
        *(bf16x4*)&outb[(long long)row*Nn + col] = pk;
      }
    }
  } else if constexpr (MODE == 1){
    short* outb = (short*)outp + bz*sO;
    #pragma unroll
    for (int ni = 0; ni < 4; ni++){
      int col = n0 + wc*64 + ni*16 + lr;
      float bv2 = bias ? bias[col] : 0.f;
      #pragma unroll
      for (int mi = 0; mi < MF; mi++){
        int row = m0 + wr*WM + mi*16 + g*4;
        bf16x4 pk;
        #pragma unroll
        for (int i = 0; i < 4; i++) pk[i] = f2bf((acc[mi][ni][i] + bv2)*scale);
        *(bf16x4*)&outb[(long long)col*M + row] = pk;
      }
    }
  } else {
    float* outb = (float*)outp + bz*sO;
    const float* rx = resid + bz*sO;
    #pragma unroll
    for (int ni = 0; ni < 4; ni++){
      int col = n0 + wc*64 + ni*16 + lr;
      float bv2 = bias[col];
      #pragma unroll
      for (int mi = 0; mi < MF; mi++){
        int row = m0 + wr*WM + mi*16 + g*4;
        long long off = (long long)col*M + row;
        float4 xr = *(const float4*)&rx[off];
        float4 o;
        o.x = acc[mi][ni][0] + bv2 + xr.x;
        o.y = acc[mi][ni][1] + bv2 + xr.y;
        o.z = acc[mi][ni][2] + bv2 + xr.z;
        o.w = acc[mi][ni][3] + bv2 + xr.w;
        *(float4*)&outb[off] = o;
      }
    }
  }
  #undef RD_AV
  #undef RD_BV
  #undef MFMA_PH
  #undef WAIT_LGKM_JI
}

extern "C" void kernel_launch(void* const* d_in, const int* in_sizes, int n_in,
                              void* d_out, int out_size, void* d_ws, size_t ws_size,
                              hipStream_t stream)
{
  const float* x   = (const float*)d_in[0];
  const float* gnw = (const float*)d_in[1];
  const float* gnb = (const float*)d_in[2];
  const float* Wq  = (const float*)d_in[3];
  const float* bq  = (const float*)d_in[4];
  const float* Wk  = (const float*)d_in[5];
  const float* bk  = (const float*)d_in[6];
  const float* Wv  = (const float*)d_in[7];
  const float* bvp = (const float*)d_in[8];
  const float* Wo  = (const float*)d_in[9];
  const float* bo  = (const float*)d_in[10];
  float* out = (float*)d_out;

  char* ws = (char*)d_ws;
  const size_t MB = 1ull << 20;
  short* h    = (short*)(ws);
  short* q    = (short*)(ws + 16*MB);
  short* kmat = (short*)(ws + 32*MB);
  short* vt   = (short*)(ws + 48*MB);
  short* ao   = (short*)(ws + 64*MB);
  short* wqb  = (short*)(ws + 80*MB);
  short* wkb  = wqb + 262144;
  short* wvb  = wkb + 262144;
  short* wob  = wvb + 262144;
  float* stats= (float*)(ws + 82*MB);
  short* S    = (short*)(ws + 84*MB);   // 128 MB (full path)

  const int LDS256 = 131072, LDS128 = 98304;
  hipFuncSetAttribute(reinterpret_cast<const void*>(&gemmF<0,256,true>),
                      hipFuncAttributeMaxDynamicSharedMemorySize, LDS256);
  hipFuncSetAttribute(reinterpret_cast<const void*>(&gemmF<0,256,false>),
                      hipFuncAttributeMaxDynamicSharedMemorySize, LDS256);
  hipFuncSetAttribute(reinterpret_cast<const void*>(&gemmF<0,128,false>),
                      hipFuncAttributeMaxDynamicSharedMemorySize, LDS128);
  hipFuncSetAttribute(reinterpret_cast<const void*>(&gemmF<1,128,false>),
                      hipFuncAttributeMaxDynamicSharedMemorySize, LDS128);
  hipFuncSetAttribute(reinterpret_cast<const void*>(&gemmF<2,128,false>),
                      hipFuncAttributeMaxDynamicSharedMemorySize, LDS128);

  dim3 blk(256);
  dim3 blk512(512);
  gn_stats<<<dim3(128), blk, 0, stream>>>(x, stats);
  gn_apply<<<dim3(64,4), blk, 0, stream>>>(x, stats, gnw, gnb, h);
  f2bf_all<<<dim3(512), blk, 0, stream>>>(Wq, Wk, Wv, Wo, wqb, wkb, wvb, wob);

  const long long sTok = 4096ll*512;
  const long long sS   = 4096ll*4096;
  const float qscale = 0.044194173824159216f;  // 1/sqrt(512)

  // Q (scale folded), K, V(transposed out)
  gemmF<0,128,false><<<dim3(16,4,4), blk512, LDS128, stream>>>(h, wqb, bq,  q,    nullptr, 4096, 512, 512, sTok, 0, sTok, qscale);
  gemmF<0,128,false><<<dim3(16,4,4), blk512, LDS128, stream>>>(h, wkb, bk,  kmat, nullptr, 4096, 512, 512, sTok, 0, sTok, 1.f);
  gemmF<1,128,false><<<dim3(16,4,4), blk512, LDS128, stream>>>(h, wvb, bvp, vt,   nullptr, 4096, 512, 512, sTok, 0, sTok, 1.f);

  if (ws_size >= 212*MB){
    gemmF<0,256,true><<<dim3(1024), blk512, LDS256, stream>>>(q, kmat, nullptr, S, nullptr, 4096, 4096, 512, sTok, sTok, sS, 1.f);
    softmax_rows<<<dim3(16384), blk, 0, stream>>>(S);
    gemmF<0,128,false><<<dim3(16,4,4), blk512, LDS128, stream>>>(S, vt, nullptr, ao, nullptr, 4096, 512, 4096, sS, sTok, sTok, 1.f);
  } else {
    for (int b = 0; b < 4; b++){
      gemmF<0,256,false><<<dim3(16,16,1), blk512, LDS256, stream>>>(q + b*sTok, kmat + b*sTok, nullptr, S, nullptr, 4096, 4096, 512, 0, 0, 0, 1.f);
      softmax_rows<<<dim3(4096), blk, 0, stream>>>(S);
      gemmF<0,128,false><<<dim3(16,4,1), blk512, LDS128, stream>>>(S, vt + b*sTok, nullptr, ao + b*sTok, nullptr, 4096, 512, 4096, 0, 0, 0, 1.f);
    }
  }

  // O-projection + bias + residual + transpose to [B, C, N] fp32
  gemmF<2,128,false><<<dim3(16,4,4), blk512, LDS128, stream>>>(ao, wob, bo, out, x, 4096, 512, 512, sTok, 0, sTok, 1.f);
}

// Round 8
// 318.082 us; speedup vs baseline: 1.1339x; 1.1339x over previous
//
#include <hip/hip_runtime.h>
#include <hip/hip_bf16.h>

typedef __attribute__((ext_vector_type(8))) short bf16x8;
typedef __attribute__((ext_vector_type(4))) short bf16x4;
typedef __attribute__((ext_vector_type(4))) float f32x4;

__device__ __forceinline__ short f2bf(float f){
  __hip_bfloat16 h = __float2bfloat16(f);
  return __builtin_bit_cast(short, h);
}
__device__ __forceinline__ float bf2f(short s){
  unsigned u = ((unsigned)(unsigned short)s) << 16;
  return __builtin_bit_cast(float, u);
}

__device__ __forceinline__ void gload_lds16(const short* g, char* l){
  __builtin_amdgcn_global_load_lds(
      (const __attribute__((address_space(1))) void*)g,
      (__attribute__((address_space(3))) void*)l, 16, 0, 0);
}

#define SB0() __builtin_amdgcn_sched_barrier(0)
#define BARRIER() do{ SB0(); __builtin_amdgcn_s_barrier(); }while(0)

// ---------------- GroupNorm stats ----------------
__global__ __launch_bounds__(256) void gn_stats(const float* __restrict__ x,
                                                float* __restrict__ stats){
  int b = blockIdx.x >> 5, g = blockIdx.x & 31;
  const float4* p = (const float4*)(x + ((long long)b*512 + g*16)*4096);
  float s = 0.f, s2 = 0.f;
  for (int i = threadIdx.x; i < 16384; i += 256){
    float4 v = p[i];
    s  += v.x + v.y + v.z + v.w;
    s2 += v.x*v.x + v.y*v.y + v.z*v.z + v.w*v.w;
  }
  #pragma unroll
  for (int o = 32; o; o >>= 1){ s += __shfl_xor(s, o); s2 += __shfl_xor(s2, o); }
  __shared__ float rs[4], rs2[4];
  int wid = threadIdx.x >> 6;
  if ((threadIdx.x & 63) == 0){ rs[wid] = s; rs2[wid] = s2; }
  __syncthreads();
  if (threadIdx.x == 0){
    float S  = rs[0]+rs[1]+rs[2]+rs[3];
    float S2 = rs2[0]+rs2[1]+rs2[2]+rs2[3];
    float mean = S * (1.f/65536.f);
    float var  = S2 * (1.f/65536.f) - mean*mean;
    stats[blockIdx.x*2]   = mean;
    stats[blockIdx.x*2+1] = rsqrtf(var + 1e-6f);
  }
}

// ------------- GN apply + transpose -> h bf16 [B,N,C] ------------------
__global__ __launch_bounds__(256) void gn_apply(const float* __restrict__ x,
                                                const float* __restrict__ stats,
                                                const float* __restrict__ gw,
                                                const float* __restrict__ gb,
                                                short* __restrict__ h){
  __shared__ float tile[128][65];
  int b  = blockIdx.y;
  int n0 = blockIdx.x * 64;
  int t  = threadIdx.x;
  const float* xb = x + (long long)b*512*4096;
  for (int cc = 0; cc < 4; cc++){
    int c0 = cc*128;
    #pragma unroll
    for (int r = 0; r < 128; r += 4){
      int c = r + (t >> 6);
      tile[c][t & 63] = xb[(long long)(c0+c)*4096 + n0 + (t & 63)];
    }
    __syncthreads();
    int n = t >> 2, cp = (t & 3)*32;
    short tmp[32];
    #pragma unroll
    for (int j = 0; j < 32; j++){
      int c = c0 + cp + j;
      float mean = stats[(b*32 + (c >> 4))*2];
      float rstd = stats[(b*32 + (c >> 4))*2 + 1];
      float v = (tile[cp+j][n] - mean)*rstd*gw[c] + gb[c];
      tmp[j] = f2bf(v);
    }
    long long ho = ((long long)b*4096 + n0 + n)*512 + c0 + cp;
    #pragma unroll
    for (int j2 = 0; j2 < 4; j2++){
      bf16x8 v8;
      #pragma unroll
      for (int e = 0; e < 8; e++) v8[e] = tmp[j2*8 + e];
      *(bf16x8*)&h[ho + j2*8] = v8;
    }
    __syncthreads();
  }
}

// ---------- fp32 -> bf16 weights ----------
__global__ __launch_bounds__(256) void f2bf_all(
    const float* __restrict__ w0, const float* __restrict__ w1,
    const float* __restrict__ w2, const float* __restrict__ w3,
    short* __restrict__ o0, short* __restrict__ o1,
    short* __restrict__ o2, short* __restrict__ o3){
  int idx = blockIdx.x*256 + threadIdx.x;
  int m = idx >> 15, r = idx & 32767;
  const float* src = (m==0) ? w0 : (m==1) ? w1 : (m==2) ? w2 : w3;
  short* dst       = (m==0) ? o0 : (m==1) ? o1 : (m==2) ? o2 : o3;
  const float4* p = (const float4*)src + (long long)r*2;
  float4 a = p[0], c = p[1];
  bf16x8 v;
  v[0]=f2bf(a.x); v[1]=f2bf(a.y); v[2]=f2bf(a.z); v[3]=f2bf(a.w);
  v[4]=f2bf(c.x); v[5]=f2bf(c.y); v[6]=f2bf(c.z); v[7]=f2bf(c.w);
  *(bf16x8*)&dst[(long long)r*8] = v;
}

// ---------------- denominator reduce: inv_den[r] = 1/sum(partial[r][0..15]) ----
__global__ __launch_bounds__(256) void reduce_den(const float* __restrict__ partial,
                                                  float* __restrict__ inv_den,
                                                  int nrows){
  int r = blockIdx.x*256 + threadIdx.x;
  if (r >= nrows) return;
  const float4* p = (const float4*)(partial + (long long)r*16);
  float4 a = p[0], b = p[1], c = p[2], d = p[3];
  float s = a.x+a.y+a.z+a.w + b.x+b.y+b.z+b.w + c.x+c.y+c.z+c.w + d.x+d.y+d.z+d.w;
  inv_den[r] = 1.f / s;
}

// ======= 256xBN bf16 GEMM, 8 waves, BK=64, 4-phase frag-ahead pipeline =======
// (K-loop identical to round-7 verified version.)
// MODE 0: bf16 [M][Nn] + bias + scale (swapped-operand direct stores)
// MODE 1: bf16 [Nn][M] transposed + bias
// MODE 2: fp32 [Nn][M] + bias + residual
// MODE 4: scores: p' = exp2(acc*log2e) bf16 [M][Nn] + per-(row,by) partial sums
// MODE 5: PV: bf16 [M][Nn], acc * inv_den[row]
// SWZ 0: natural grid. SWZ 1: scores 4x4-region XCD decode (1024 blocks).
// SWZ 2: PV B-panel-resident XCD decode (256 blocks).
template<int MODE, int BN, int SWZ>
__global__ __launch_bounds__(512, 2) void gemmF(
    const short* __restrict__ A, const short* __restrict__ Bw,
    const float* __restrict__ bias,
    void* __restrict__ outp, const float* __restrict__ resid,
    int M, int Nn, int Kd,
    long long sA, long long sB, long long sO, float scale,
    const float* __restrict__ dptr, float* __restrict__ partial)
{
  constexpr int WARPS_N = BN/64;          // 4 or 2
  constexpr int WARPS_M = 8/WARPS_N;      // 2 or 4
  constexpr int WM = 256/WARPS_M;         // 128 or 64
  constexpr int MF = WM/16;               // 8 or 4
  constexpr int QR = MF/4;                // 2 or 1 rows per quadrant-phase
  constexpr int ABYT = 32768;             // A: 256x64 bf16
  constexpr int BBYT = BN*128;
  constexpr int BUFSZ = ABYT + BBYT;
  constexpr int BH = BBYT/16384;          // B half-tiles: 2 or 1
  extern __shared__ char smem[];

  int bx, by, bz;
  if constexpr (SWZ == 1){
    // 1024 blocks: XCD owns 4x4 (bx,by) regions; 2 regions live per XCD ~ L2.
    int id = blockIdx.x;
    int xcd = id & 7, s = id >> 3;
    int region = xcd + ((s >> 4) << 3);   // 0..63
    int o = s & 15;
    bz = region >> 4;
    bx = (region & 3)*4 + (o & 3);
    by = ((region >> 2) & 3)*4 + (o >> 2);
  } else if constexpr (SWZ == 2){
    // 256 blocks: each XCD owns 2 (by,bz) combos -> its 2 B-panels stay in L2.
    int id = blockIdx.x;
    int xcd = id & 7, s = id >> 3;        // s 0..31
    int combo = xcd*2 + (s & 1);          // 0..15
    by = combo & 3; bz = combo >> 2;
    bx = s >> 1;                          // 0..15
  } else { bx = blockIdx.x; by = blockIdx.y; bz = blockIdx.z; }

  const short* Ab = A + bz*sA;
  const short* Bb = Bw + bz*sB;
  const int m0 = bx*256, n0 = by*BN;
  const int t = threadIdx.x;
  const int lane = t & 63, wid = t >> 6;
  const int g = lane >> 4, lr = lane & 15;
  const int wr = wid / WARPS_N, wc = wid % WARPS_N;
  const long long KdLL = Kd;

  const int r0 = t >> 3, c8 = t & 7;

  auto STAGE_A = [&](int kt, int buf, int h){
    char* d = smem + buf*BUFSZ + h*16384 + t*16;
    #pragma unroll
    for (int j = 0; j < 2; j++){
      int row = h*128 + j*64 + r0;
      gload_lds16(Ab + (long long)(m0+row)*KdLL + (long long)kt*64 + ((c8 ^ (row&7))*8),
                  d + j*8192);
    }
  };
  auto STAGE_B = [&](int kt, int buf, int h){
    char* d = smem + buf*BUFSZ + ABYT + h*16384 + t*16;
    #pragma unroll
    for (int j = 0; j < 2; j++){
      int row = h*128 + j*64 + r0;
      gload_lds16(Bb + (long long)(n0+row)*KdLL + (long long)kt*64 + ((c8 ^ (row&7))*8),
                  d + j*8192);
    }
  };

  int roA[MF], swA[MF], roB[4], swB[4];
  #pragma unroll
  for (int mf = 0; mf < MF; mf++){
    int ra = wr*WM + mf*16 + lr;
    roA[mf] = (ra>>7)*16384 + (ra&127)*128; swA[mf] = ra & 7;
  }
  #pragma unroll
  for (int nf = 0; nf < 4; nf++){
    int rb = wc*64 + nf*16 + lr;
    roB[nf] = ABYT + (rb>>7)*16384 + (rb&127)*128; swB[nf] = rb & 7;
  }

  f32x4 acc[MF][4];
  #pragma unroll
  for (int i = 0; i < MF; i++)
    #pragma unroll
    for (int j = 0; j < 4; j++)
      acc[i][j] = f32x4{0.f,0.f,0.f,0.f};
  bf16x8 av[2][QR][2], bv[4][2];

  #define RD_AV(SET, Q, BASE) do{                                         \
    _Pragma("unroll")                                                     \
    for (int _i = 0; _i < QR; _i++)                                       \
      _Pragma("unroll")                                                   \
      for (int _ks = 0; _ks < 2; _ks++){                                  \
        int _x = (Q)*QR + _i;                                             \
        av[SET][_i][_ks] = *(const bf16x8*)((BASE) + roA[_x] +            \
                            (((_ks*4+g) ^ swA[_x])<<4));                  \
      } }while(0)

  #define RD_BV(BASE) do{                                                 \
    _Pragma("unroll")                                                     \
    for (int _n = 0; _n < 4; _n++)                                        \
      _Pragma("unroll")                                                   \
      for (int _ks = 0; _ks < 2; _ks++)                                   \
        bv[_n][_ks] = *(const bf16x8*)((BASE) + roB[_n] +                 \
                            (((_ks*4+g) ^ swB[_n])<<4));                  \
    }while(0)

  #define MFMA_PH(Q, SET) do{                                             \
    __builtin_amdgcn_s_setprio(1);                                        \
    _Pragma("unroll")                                                     \
    for (int _ks = 0; _ks < 2; _ks++)                                     \
      _Pragma("unroll")                                                   \
      for (int _n = 0; _n < 4; _n++)                                      \
        _Pragma("unroll")                                                 \
        for (int _i = 0; _i < QR; _i++){                                  \
          if constexpr (MODE == 1 || MODE == 2)                           \
            acc[(Q)*QR+_i][_n] = __builtin_amdgcn_mfma_f32_16x16x32_bf16( \
              av[SET][_i][_ks], bv[_n][_ks], acc[(Q)*QR+_i][_n], 0,0,0);  \
          else                                                            \
            acc[(Q)*QR+_i][_n] = __builtin_amdgcn_mfma_f32_16x16x32_bf16( \
              bv[_n][_ks], av[SET][_i][_ks], acc[(Q)*QR+_i][_n], 0,0,0);  \
        }                                                                 \
    __builtin_amdgcn_s_setprio(0); }while(0)

  #define WAIT_LGKM_JI() do{                                              \
    if constexpr (QR == 2) asm volatile("s_waitcnt lgkmcnt(4)":::"memory");\
    else                   asm volatile("s_waitcnt lgkmcnt(2)":::"memory");\
    SB0(); }while(0)

  const int NT = Kd >> 6;

  // prologue: A(0), B(0), B(1); leave B(1) in flight
  STAGE_A(0,0,0); STAGE_A(0,0,1);
  STAGE_B(0,0,0); if constexpr (BH==2) STAGE_B(0,0,1);
  STAGE_B(1,1,0); if constexpr (BH==2) STAGE_B(1,1,1);
  if constexpr (BH==2) asm volatile("s_waitcnt vmcnt(4)":::"memory");
  else                 asm volatile("s_waitcnt vmcnt(2)":::"memory");
  SB0();
  __builtin_amdgcn_s_barrier();
  RD_AV(0, 0, smem);                  // av0(tile0) -> set0

  for (int kt = 0; kt < NT; ++kt){
    char* bc  = smem + (kt & 1)*BUFSZ;
    char* bn_ = smem + ((kt & 1)^1)*BUFSZ;
    // ---- ph0
    RD_BV(bc);
    RD_AV(1, 1, bc);
    if (kt+1 < NT) STAGE_A(kt+1, (kt&1)^1, 0);
    BARRIER();
    WAIT_LGKM_JI();
    MFMA_PH(0, 0);
    BARRIER();
    // ---- ph1
    RD_AV(0, 2, bc);
    if (kt+1 < NT) STAGE_A(kt+1, (kt&1)^1, 1);
    BARRIER();
    WAIT_LGKM_JI();
    MFMA_PH(1, 1);
    BARRIER();
    // ---- ph2
    RD_AV(1, 3, bc);
    if (kt+2 < NT) STAGE_B(kt+2, kt&1, 0);
    BARRIER();
    if (kt+2 < NT) asm volatile("s_waitcnt vmcnt(2)":::"memory");
    else           asm volatile("s_waitcnt vmcnt(0)":::"memory");
    SB0();
    WAIT_LGKM_JI();
    MFMA_PH(2, 0);
    BARRIER();
    // ---- ph3
    if (kt+1 < NT) RD_AV(0, 0, bn_);
    if constexpr (BH==2){ if (kt+2 < NT) STAGE_B(kt+2, kt&1, 1); }
    BARRIER();
    if (kt+1 < NT){ WAIT_LGKM_JI(); }
    else { asm volatile("s_waitcnt lgkmcnt(0)":::"memory"); SB0(); }
    MFMA_PH(3, 1);
    BARRIER();
  }

  if constexpr (MODE == 0){
    short* outb = (short*)outp + bz*sO;
    const bool hb = (bias != nullptr);
    #pragma unroll
    for (int mi = 0; mi < MF; mi++){
      int row = m0 + wr*WM + mi*16 + lr;
      #pragma unroll
      for (int ni = 0; ni < 4; ni++){
        int col = n0 + wc*64 + ni*16 + g*4;
        float b0=0.f,b1=0.f,b2=0.f,b3=0.f;
        if (hb){ float4 bb = *(const float4*)&bias[col]; b0=bb.x; b1=bb.y; b2=bb.z; b3=bb.w; }
        bf16x4 pk;
        pk[0] = f2bf((acc[mi][ni][0] + b0)*scale);
        pk[1] = f2bf((acc[mi][ni][1] + b1)*scale);
        pk[2] = f2bf((acc[mi][ni][2] + b2)*scale);
        pk[3] = f2bf((acc[mi][ni][3] + b3)*scale);
        *(bf16x4*)&outb[(long long)row*Nn + col] = pk;
      }
    }
  } else if constexpr (MODE == 4){
    // exp epilogue + deterministic per-(row, by) partial sums
    short* outb = (short*)outp + bz*sO;
    float* rowpart = (float*)smem;      // [256][WARPS_N], LDS free after K-loop
    constexpr float LOG2E = 1.4426950408889634f;
    #pragma unroll
    for (int mi = 0; mi < MF; mi++){
      int lrow = wr*WM + mi*16 + lr;
      int row  = m0 + lrow;
      float rs = 0.f;
      #pragma unroll
      for (int ni = 0; ni < 4; ni++){
        int col = n0 + wc*64 + ni*16 + g*4;
        bf16x4 pk;
        #pragma unroll
        for (int i = 0; i < 4; i++){
          float p = exp2f(acc[mi][ni][i]*LOG2E);
          rs += p;
          pk[i] = f2bf(p);
        }
        *(bf16x4*)&outb[(long long)row*Nn + col] = pk;
      }
      rs += __shfl_xor(rs, 16);
      rs += __shfl_xor(rs, 32);
      if (g == 0) rowpart[lrow*WARPS_N + wc] = rs;
    }
    __syncthreads();
    if (t < 256){
      float s2 = 0.f;
      #pragma unroll
      for (int j = 0; j < WARPS_N; j++) s2 += rowpart[t*WARPS_N + j];
      partial[((long long)bz*4096 + m0 + t)*16 + by] = s2;
    }
  } else if constexpr (MODE == 5){
    short* outb = (short*)outp + bz*sO;
    const float* dd = dptr + (long long)bz*M;
    #pragma unroll
    for (int mi = 0; mi < MF; mi++){
      int row = m0 + wr*WM + mi*16 + lr;
      float inv = dd[row];
      #pragma unroll
      for (int ni = 0; ni < 4; ni++){
        int col = n0 + wc*64 + ni*16 + g*4;
        bf16x4 pk;
        #pragma unroll
        for (int i = 0; i < 4; i++) pk[i] = f2bf(acc[mi][ni][i]*inv);
        *(bf16x4*)&outb[(long long)row*Nn + col] = pk;
      }
    }
  } else if constexpr (MODE == 1){
    short* outb = (short*)outp + bz*sO;
    #pragma unroll
    for (int ni = 0; ni < 4; ni++){
      int col = n0 + wc*64 + ni*16 + lr;
      float bv2 = bias ? bias[col] : 0.f;
      #pragma unroll
      for (int mi = 0; mi < MF; mi++){
        int row = m0 + wr*WM + mi*16 + g*4;
        bf16x4 pk;
        #pragma unroll
        for (int i = 0; i < 4; i++) pk[i] = f2bf((acc[mi][ni][i] + bv2)*scale);
        *(bf16x4*)&outb[(long long)col*M + row] = pk;
      }
    }
  } else {
    float* outb = (float*)outp + bz*sO;
    const float* rx = resid + bz*sO;
    #pragma unroll
    for (int ni = 0; ni < 4; ni++){
      int col = n0 + wc*64 + ni*16 + lr;
      float bv2 = bias[col];
      #pragma unroll
      for (int mi = 0; mi < MF; mi++){
        int row = m0 + wr*WM + mi*16 + g*4;
        long long off = (long long)col*M + row;
        float4 xr = *(const float4*)&rx[off];
        float4 o;
        o.x = acc[mi][ni][0] + bv2 + xr.x;
        o.y = acc[mi][ni][1] + bv2 + xr.y;
        o.z = acc[mi][ni][2] + bv2 + xr.z;
        o.w = acc[mi][ni][3] + bv2 + xr.w;
        *(float4*)&outb[off] = o;
      }
    }
  }
  #undef RD_AV
  #undef RD_BV
  #undef MFMA_PH
  #undef WAIT_LGKM_JI
}

extern "C" void kernel_launch(void* const* d_in, const int* in_sizes, int n_in,
                              void* d_out, int out_size, void* d_ws, size_t ws_size,
                              hipStream_t stream)
{
  const float* x   = (const float*)d_in[0];
  const float* gnw = (const float*)d_in[1];
  const float* gnb = (const float*)d_in[2];
  const float* Wq  = (const float*)d_in[3];
  const float* bq  = (const float*)d_in[4];
  const float* Wk  = (const float*)d_in[5];
  const float* bk  = (const float*)d_in[6];
  const float* Wv  = (const float*)d_in[7];
  const float* bvp = (const float*)d_in[8];
  const float* Wo  = (const float*)d_in[9];
  const float* bo  = (const float*)d_in[10];
  float* out = (float*)d_out;

  char* ws = (char*)d_ws;
  const size_t MB = 1ull << 20;
  short* h      = (short*)(ws);
  short* q      = (short*)(ws + 16*MB);
  short* kmat   = (short*)(ws + 32*MB);
  short* vt     = (short*)(ws + 48*MB);
  short* ao     = (short*)(ws + 64*MB);
  short* wqb    = (short*)(ws + 80*MB);
  short* wkb    = wqb + 262144;
  short* wvb    = wkb + 262144;
  short* wob    = wvb + 262144;
  float* stats  = (float*)(ws + 82*MB);
  float* inv_den= (float*)(ws + 82*MB + 8192);    // 64 KB
  float* partial= (float*)(ws + 83*MB);           // 1 MB: [4][4096][16]
  short* S      = (short*)(ws + 84*MB);           // 128 MB (full path)

  const int LDS256 = 131072, LDS128 = 98304;
  hipFuncSetAttribute(reinterpret_cast<const void*>(&gemmF<4,256,1>),
                      hipFuncAttributeMaxDynamicSharedMemorySize, LDS256);
  hipFuncSetAttribute(reinterpret_cast<const void*>(&gemmF<4,256,0>),
                      hipFuncAttributeMaxDynamicSharedMemorySize, LDS256);
  hipFuncSetAttribute(reinterpret_cast<const void*>(&gemmF<0,128,0>),
                      hipFuncAttributeMaxDynamicSharedMemorySize, LDS128);
  hipFuncSetAttribute(reinterpret_cast<const void*>(&gemmF<1,128,0>),
                      hipFuncAttributeMaxDynamicSharedMemorySize, LDS128);
  hipFuncSetAttribute(reinterpret_cast<const void*>(&gemmF<2,128,0>),
                      hipFuncAttributeMaxDynamicSharedMemorySize, LDS128);
  hipFuncSetAttribute(reinterpret_cast<const void*>(&gemmF<5,128,2>),
                      hipFuncAttributeMaxDynamicSharedMemorySize, LDS128);
  hipFuncSetAttribute(reinterpret_cast<const void*>(&gemmF<5,128,0>),
                      hipFuncAttributeMaxDynamicSharedMemorySize, LDS128);

  dim3 blk(256);
  dim3 blk512(512);
  gn_stats<<<dim3(128), blk, 0, stream>>>(x, stats);
  gn_apply<<<dim3(64,4), blk, 0, stream>>>(x, stats, gnw, gnb, h);
  f2bf_all<<<dim3(512), blk, 0, stream>>>(Wq, Wk, Wv, Wo, wqb, wkb, wvb, wob);

  const long long sTok = 4096ll*512;
  const long long sS   = 4096ll*4096;
  const float qscale = 0.044194173824159216f;  // 1/sqrt(512)

  // Q (scale folded), K, V(transposed out)
  gemmF<0,128,0><<<dim3(16,4,4), blk512, LDS128, stream>>>(h, wqb, bq,  q,    nullptr, 4096, 512, 512, sTok, 0, sTok, qscale, nullptr, nullptr);
  gemmF<0,128,0><<<dim3(16,4,4), blk512, LDS128, stream>>>(h, wkb, bk,  kmat, nullptr, 4096, 512, 512, sTok, 0, sTok, 1.f, nullptr, nullptr);
  gemmF<1,128,0><<<dim3(16,4,4), blk512, LDS128, stream>>>(h, wvb, bvp, vt,   nullptr, 4096, 512, 512, sTok, 0, sTok, 1.f, nullptr, nullptr);

  if (ws_size >= 212*MB){
    // scores with fused exp + partial row sums
    gemmF<4,256,1><<<dim3(1024), blk512, LDS256, stream>>>(q, kmat, nullptr, S, nullptr, 4096, 4096, 512, sTok, sTok, sS, 1.f, nullptr, partial);
    reduce_den<<<dim3(64), blk, 0, stream>>>(partial, inv_den, 16384);
    // PV with fused 1/den
    gemmF<5,128,2><<<dim3(256), blk512, LDS128, stream>>>(S, vt, nullptr, ao, nullptr, 4096, 512, 4096, sS, sTok, sTok, 1.f, inv_den, nullptr);
  } else {
    for (int b = 0; b < 4; b++){
      gemmF<4,256,0><<<dim3(16,16,1), blk512, LDS256, stream>>>(q + b*sTok, kmat + b*sTok, nullptr, S, nullptr, 4096, 4096, 512, 0, 0, 0, 1.f, nullptr, partial);
      reduce_den<<<dim3(16), blk, 0, stream>>>(partial, inv_den, 4096);
      gemmF<5,128,0><<<dim3(16,4,1), blk512, LDS128, stream>>>(S, vt + b*sTok, nullptr, ao + b*sTok, nullptr, 4096, 512, 4096, 0, 0, 0, 1.f, inv_den, nullptr);
    }
  }

  // O-projection + bias + residual + transpose to [B, C, N] fp32
  gemmF<2,128,0><<<dim3(16,4,4), blk512, LDS128, stream>>>(ao, wob, bo, out, x, 4096, 512, 512, sTok, 0, sTok, 1.f, nullptr, nullptr);
}

// Round 9
// 317.011 us; speedup vs baseline: 1.1377x; 1.0034x over previous
//
#include <hip/hip_runtime.h>
#include <hip/hip_bf16.h>

typedef __attribute__((ext_vector_type(8))) short bf16x8;
typedef __attribute__((ext_vector_type(4))) short bf16x4;
typedef __attribute__((ext_vector_type(4))) float f32x4;

__device__ __forceinline__ short f2bf(float f){
  __hip_bfloat16 h = __float2bfloat16(f);
  return __builtin_bit_cast(short, h);
}
__device__ __forceinline__ float bf2f(short s){
  unsigned u = ((unsigned)(unsigned short)s) << 16;
  return __builtin_bit_cast(float, u);
}

__device__ __forceinline__ void gload_lds16(const short* g, char* l){
  __builtin_amdgcn_global_load_lds(
      (const __attribute__((address_space(1))) void*)g,
      (__attribute__((address_space(3))) void*)l, 16, 0, 0);
}

#define SB0() __builtin_amdgcn_sched_barrier(0)

// ---------------- GroupNorm stats ----------------
__global__ __launch_bounds__(256) void gn_stats(const float* __restrict__ x,
                                                float* __restrict__ stats){
  int b = blockIdx.x >> 5, g = blockIdx.x & 31;
  const float4* p = (const float4*)(x + ((long long)b*512 + g*16)*4096);
  float s = 0.f, s2 = 0.f;
  for (int i = threadIdx.x; i < 16384; i += 256){
    float4 v = p[i];
    s  += v.x + v.y + v.z + v.w;
    s2 += v.x*v.x + v.y*v.y + v.z*v.z + v.w*v.w;
  }
  #pragma unroll
  for (int o = 32; o; o >>= 1){ s += __shfl_xor(s, o); s2 += __shfl_xor(s2, o); }
  __shared__ float rs[4], rs2[4];
  int wid = threadIdx.x >> 6;
  if ((threadIdx.x & 63) == 0){ rs[wid] = s; rs2[wid] = s2; }
  __syncthreads();
  if (threadIdx.x == 0){
    float S  = rs[0]+rs[1]+rs[2]+rs[3];
    float S2 = rs2[0]+rs2[1]+rs2[2]+rs2[3];
    float mean = S * (1.f/65536.f);
    float var  = S2 * (1.f/65536.f) - mean*mean;
    stats[blockIdx.x*2]   = mean;
    stats[blockIdx.x*2+1] = rsqrtf(var + 1e-6f);
  }
}

// ------------- GN apply + transpose -> h bf16 [B,N,C] ------------------
__global__ __launch_bounds__(256) void gn_apply(const float* __restrict__ x,
                                                const float* __restrict__ stats,
                                                const float* __restrict__ gw,
                                                const float* __restrict__ gb,
                                                short* __restrict__ h){
  __shared__ float tile[128][65];
  int b  = blockIdx.y;
  int n0 = blockIdx.x * 64;
  int t  = threadIdx.x;
  const float* xb = x + (long long)b*512*4096;
  for (int cc = 0; cc < 4; cc++){
    int c0 = cc*128;
    #pragma unroll
    for (int r = 0; r < 128; r += 4){
      int c = r + (t >> 6);
      tile[c][t & 63] = xb[(long long)(c0+c)*4096 + n0 + (t & 63)];
    }
    __syncthreads();
    int n = t >> 2, cp = (t & 3)*32;
    short tmp[32];
    #pragma unroll
    for (int j = 0; j < 32; j++){
      int c = c0 + cp + j;
      float mean = stats[(b*32 + (c >> 4))*2];
      float rstd = stats[(b*32 + (c >> 4))*2 + 1];
      float v = (tile[cp+j][n] - mean)*rstd*gw[c] + gb[c];
      tmp[j] = f2bf(v);
    }
    long long ho = ((long long)b*4096 + n0 + n)*512 + c0 + cp;
    #pragma unroll
    for (int j2 = 0; j2 < 4; j2++){
      bf16x8 v8;
      #pragma unroll
      for (int e = 0; e < 8; e++) v8[e] = tmp[j2*8 + e];
      *(bf16x8*)&h[ho + j2*8] = v8;
    }
    __syncthreads();
  }
}

// ---------- fp32 -> bf16 weights ----------
__global__ __launch_bounds__(256) void f2bf_all(
    const float* __restrict__ w0, const float* __restrict__ w1,
    const float* __restrict__ w2, const float* __restrict__ w3,
    short* __restrict__ o0, short* __restrict__ o1,
    short* __restrict__ o2, short* __restrict__ o3){
  int idx = blockIdx.x*256 + threadIdx.x;
  int m = idx >> 15, r = idx & 32767;
  const float* src = (m==0) ? w0 : (m==1) ? w1 : (m==2) ? w2 : w3;
  short* dst       = (m==0) ? o0 : (m==1) ? o1 : (m==2) ? o2 : o3;
  const float4* p = (const float4*)src + (long long)r*2;
  float4 a = p[0], c = p[1];
  bf16x8 v;
  v[0]=f2bf(a.x); v[1]=f2bf(a.y); v[2]=f2bf(a.z); v[3]=f2bf(a.w);
  v[4]=f2bf(c.x); v[5]=f2bf(c.y); v[6]=f2bf(c.z); v[7]=f2bf(c.w);
  *(bf16x8*)&dst[(long long)r*8] = v;
}

// ---------------- denominator reduce ----------------
__global__ __launch_bounds__(256) void reduce_den(const float* __restrict__ partial,
                                                  float* __restrict__ inv_den,
                                                  int nrows){
  int r = blockIdx.x*256 + threadIdx.x;
  if (r >= nrows) return;
  const float4* p = (const float4*)(partial + (long long)r*16);
  float4 a = p[0], b = p[1], c = p[2], d = p[3];
  float s = a.x+a.y+a.z+a.w + b.x+b.y+b.z+b.w + c.x+c.y+c.z+c.w + d.x+d.y+d.z+d.w;
  inv_den[r] = 1.f / s;
}

// ======= 256xBN bf16 GEMM, 8 waves, BK=64, dbuf, counted vmcnt ===============
// K-loop: one compiler-scheduled read+MFMA region per K-tile (no manual lgkm
// waits, no per-phase barriers -> compiler emits fine-grained lgkmcnt and
// interleaves ds_read with MFMA; m97/m141 evidence). SB0 only guards the
// staging race points. Loads stay in flight across barriers (vmcnt(LOADS)).
// MODE 0: bf16 [M][Nn] + bias + scale (swapped-operand direct stores)
// MODE 1: bf16 [Nn][M] transposed + bias
// MODE 2: fp32 [Nn][M] + bias + residual
// MODE 4: scores: p' = exp(acc) bf16 [M][Nn] + per-(row,by) partial sums
// MODE 5: PV: bf16 [M][Nn], acc * inv_den[row]
template<int MODE, int BN, int SWZ>
__global__ __launch_bounds__(512, 2) void gemmF(
    const short* __restrict__ A, const short* __restrict__ Bw,
    const float* __restrict__ bias,
    void* __restrict__ outp, const float* __restrict__ resid,
    int M, int Nn, int Kd,
    long long sA, long long sB, long long sO, float scale,
    const float* __restrict__ dptr, float* __restrict__ partial)
{
  constexpr int WARPS_N = BN/64;
  constexpr int WARPS_M = 8/WARPS_N;
  constexpr int WM = 256/WARPS_M;         // 128 or 64
  constexpr int MF = WM/16;               // 8 or 4
  constexpr int ABYT = 32768;
  constexpr int BBYT = BN*128;
  constexpr int BUFSZ = ABYT + BBYT;
  constexpr int BH = BBYT/16384;          // 2 or 1
  constexpr int LOADS = 4 + 2*BH;         // per-thread gloads per K-tile (8 or 6)
  extern __shared__ char smem[];

  int bx, by, bz;
  if constexpr (SWZ == 1){
    int id = blockIdx.x;
    int xcd = id & 7, s = id >> 3;
    int region = xcd + ((s >> 4) << 3);
    int o = s & 15;
    bz = region >> 4;
    bx = (region & 3)*4 + (o & 3);
    by = ((region >> 2) & 3)*4 + (o >> 2);
  } else if constexpr (SWZ == 2){
    int id = blockIdx.x;
    int xcd = id & 7, s = id >> 3;
    int combo = xcd*2 + (s & 1);
    by = combo & 3; bz = combo >> 2;
    bx = s >> 1;
  } else { bx = blockIdx.x; by = blockIdx.y; bz = blockIdx.z; }

  const short* Ab = A + bz*sA;
  const short* Bb = Bw + bz*sB;
  const int m0 = bx*256, n0 = by*BN;
  const int t = threadIdx.x;
  const int lane = t & 63, wid = t >> 6;
  const int g = lane >> 4, lr = lane & 15;
  const int wr = wid / WARPS_N, wc = wid % WARPS_N;
  const long long KdLL = Kd;

  const int r0 = t >> 3, c8 = t & 7;

  auto STAGE_A = [&](int kt, int buf, int h){
    char* d = smem + buf*BUFSZ + h*16384 + t*16;
    #pragma unroll
    for (int j = 0; j < 2; j++){
      int row = h*128 + j*64 + r0;
      gload_lds16(Ab + (long long)(m0+row)*KdLL + (long long)kt*64 + ((c8 ^ (row&7))*8),
                  d + j*8192);
    }
  };
  auto STAGE_B = [&](int kt, int buf, int h){
    char* d = smem + buf*BUFSZ + ABYT + h*16384 + t*16;
    #pragma unroll
    for (int j = 0; j < 2; j++){
      int row = h*128 + j*64 + r0;
      gload_lds16(Bb + (long long)(n0+row)*KdLL + (long long)kt*64 + ((c8 ^ (row&7))*8),
                  d + j*8192);
    }
  };

  int roA[MF], swA[MF], roB[4], swB[4];
  #pragma unroll
  for (int mf = 0; mf < MF; mf++){
    int ra = wr*WM + mf*16 + lr;
    roA[mf] = (ra>>7)*16384 + (ra&127)*128; swA[mf] = ra & 7;
  }
  #pragma unroll
  for (int nf = 0; nf < 4; nf++){
    int rb = wc*64 + nf*16 + lr;
    roB[nf] = ABYT + (rb>>7)*16384 + (rb&127)*128; swB[nf] = rb & 7;
  }

  f32x4 acc[MF][4];
  #pragma unroll
  for (int i = 0; i < MF; i++)
    #pragma unroll
    for (int j = 0; j < 4; j++)
      acc[i][j] = f32x4{0.f,0.f,0.f,0.f};

  const int NT = Kd >> 6;

  // prologue: stage tiles 0 and 1; wait tile0; tile1 stays in flight
  STAGE_A(0,0,0); STAGE_A(0,0,1);
  STAGE_B(0,0,0); if constexpr (BH==2) STAGE_B(0,0,1);
  STAGE_A(1,1,0); STAGE_A(1,1,1);
  STAGE_B(1,1,0); if constexpr (BH==2) STAGE_B(1,1,1);
  if constexpr (BH==2) asm volatile("s_waitcnt vmcnt(8)":::"memory");
  else                 asm volatile("s_waitcnt vmcnt(6)":::"memory");
  SB0();
  __builtin_amdgcn_s_barrier();

  for (int kt = 0; kt < NT; ++kt){
    char* base = smem + (kt & 1)*BUFSZ;
    // ---- one free-scheduling region: all ds_reads + all MFMAs ----
    bf16x8 av[MF][2], bv[4][2];
    #pragma unroll
    for (int n = 0; n < 4; n++)
      #pragma unroll
      for (int ks = 0; ks < 2; ks++)
        bv[n][ks] = *(const bf16x8*)(base + roB[n] + (((ks*4+g) ^ swB[n])<<4));
    #pragma unroll
    for (int m = 0; m < MF; m++)
      #pragma unroll
      for (int ks = 0; ks < 2; ks++)
        av[m][ks] = *(const bf16x8*)(base + roA[m] + (((ks*4+g) ^ swA[m])<<4));
    #pragma unroll
    for (int ks = 0; ks < 2; ks++)
      #pragma unroll
      for (int m = 0; m < MF; m++)
        #pragma unroll
        for (int n = 0; n < 4; n++){
          if constexpr (MODE == 1 || MODE == 2)
            acc[m][n] = __builtin_amdgcn_mfma_f32_16x16x32_bf16(av[m][ks], bv[n][ks], acc[m][n], 0,0,0);
          else
            acc[m][n] = __builtin_amdgcn_mfma_f32_16x16x32_bf16(bv[n][ks], av[m][ks], acc[m][n], 0,0,0);
        }
    // ---- barrier1: all waves done reading this buffer ----
    SB0();
    __builtin_amdgcn_s_barrier();
    SB0();                      // STAGE must not hoist above barrier1
    if (kt + 2 < NT){
      STAGE_A(kt+2, kt&1, 0); STAGE_A(kt+2, kt&1, 1);
      STAGE_B(kt+2, kt&1, 0); if constexpr (BH==2) STAGE_B(kt+2, kt&1, 1);
      if constexpr (BH==2) asm volatile("s_waitcnt vmcnt(8)":::"memory");
      else                 asm volatile("s_waitcnt vmcnt(6)":::"memory");
    } else {
      asm volatile("s_waitcnt vmcnt(0)":::"memory");
    }
    // asm memory clobber above blocks next-iter read hoisting
    __builtin_amdgcn_s_barrier();   // barrier2: tile kt+1 visible to all waves
  }

  if constexpr (MODE == 0){
    short* outb = (short*)outp + bz*sO;
    const bool hb = (bias != nullptr);
    #pragma unroll
    for (int mi = 0; mi < MF; mi++){
      int row = m0 + wr*WM + mi*16 + lr;
      #pragma unroll
      for (int ni = 0; ni < 4; ni++){
        int col = n0 + wc*64 + ni*16 + g*4;
        float b0=0.f,b1=0.f,b2=0.f,b3=0.f;
        if (hb){ float4 bb = *(const float4*)&bias[col]; b0=bb.x; b1=bb.y; b2=bb.z; b3=bb.w; }
        bf16x4 pk;
        pk[0] = f2bf((acc[mi][ni][0] + b0)*scale);
        pk[1] = f2bf((acc[mi][ni][1] + b1)*scale);
        pk[2] = f2bf((acc[mi][ni][2] + b2)*scale);
        pk[3] = f2bf((acc[mi][ni][3] + b3)*scale);
        *(bf16x4*)&outb[(long long)row*Nn + col] = pk;
      }
    }
  } else if constexpr (MODE == 4){
    short* outb = (short*)outp + bz*sO;
    float* rowpart = (float*)smem;
    constexpr float LOG2E = 1.4426950408889634f;
    #pragma unroll
    for (int mi = 0; mi < MF; mi++){
      int lrow = wr*WM + mi*16 + lr;
      int row  = m0 + lrow;
      float rs = 0.f;
      #pragma unroll
      for (int ni = 0; ni < 4; ni++){
        int col = n0 + wc*64 + ni*16 + g*4;
        bf16x4 pk;
        #pragma unroll
        for (int i = 0; i < 4; i++){
          float p = exp2f(acc[mi][ni][i]*LOG2E);
          rs += p;
          pk[i] = f2bf(p);
        }
        *(bf16x4*)&outb[(long long)row*Nn + col] = pk;
      }
      rs += __shfl_xor(rs, 16);
      rs += __shfl_xor(rs, 32);
      if (g == 0) rowpart[lrow*WARPS_N + wc] = rs;
    }
    __syncthreads();
    if (t < 256){
      float s2 = 0.f;
      #pragma unroll
      for (int j = 0; j < WARPS_N; j++) s2 += rowpart[t*WARPS_N + j];
      partial[((long long)bz*4096 + m0 + t)*16 + by] = s2;
    }
  } else if constexpr (MODE == 5){
    short* outb = (short*)outp + bz*sO;
    const float* dd = dptr + (long long)bz*M;
    #pragma unroll
    for (int mi = 0; mi < MF; mi++){
      int row = m0 + wr*WM + mi*16 + lr;
      float inv = dd[row];
      #pragma unroll
      for (int ni = 0; ni < 4; ni++){
        int col = n0 + wc*64 + ni*16 + g*4;
        bf16x4 pk;
        #pragma unroll
        for (int i = 0; i < 4; i++) pk[i] = f2bf(acc[mi][ni][i]*inv);
        *(bf16x4*)&outb[(long long)row*Nn + col] = pk;
      }
    }
  } else if constexpr (MODE == 1){
    short* outb = (short*)outp + bz*sO;
    #pragma unroll
    for (int ni = 0; ni < 4; ni++){
      int col = n0 + wc*64 + ni*16 + lr;
      float bv2 = bias ? bias[col] : 0.f;
      #pragma unroll
      for (int mi = 0; mi < MF; mi++){
        int row = m0 + wr*WM + mi*16 + g*4;
        bf16x4 pk;
        #pragma unroll
        for (int i = 0; i < 4; i++) pk[i] = f2bf((acc[mi][ni][i] + bv2)*scale);
        *(bf16x4*)&outb[(long long)col*M + row] = pk;
      }
    }
  } else {
    float* outb = (float*)outp + bz*sO;
    const float* rx = resid + bz*sO;
    #pragma unroll
    for (int ni = 0; ni < 4; ni++){
      int col = n0 + wc*64 + ni*16 + lr;
      float bv2 = bias[col];
      #pragma unroll
      for (int mi = 0; mi < MF; mi++){
        int row = m0 + wr*WM + mi*16 + g*4;
        long long off = (long long)col*M + row;
        float4 xr = *(const float4*)&rx[off];
        float4 o;
        o.x = acc[mi][ni][0] + bv2 + xr.x;
        o.y = acc[mi][ni][1] + bv2 + xr.y;
        o.z = acc[mi][ni][2] + bv2 + xr.z;
        o.w = acc[mi][ni][3] + bv2 + xr.w;
        *(float4*)&outb[off] = o;
      }
    }
  }
}

extern "C" void kernel_launch(void* const* d_in, const int* in_sizes, int n_in,
                              void* d_out, int out_size, void* d_ws, size_t ws_size,
                              hipStream_t stream)
{
  const float* x   = (const float*)d_in[0];
  const float* gnw = (const float*)d_in[1];
  const float* gnb = (const float*)d_in[2];
  const float* Wq  = (const float*)d_in[3];
  const float* bq  = (const float*)d_in[4];
  const float* Wk  = (const float*)d_in[5];
  const float* bk  = (const float*)d_in[6];
  const float* Wv  = (const float*)d_in[7];
  const float* bvp = (const float*)d_in[8];
  const float* Wo  = (const float*)d_in[9];
  const float* bo  = (const float*)d_in[10];
  float* out = (float*)d_out;

  char* ws = (char*)d_ws;
  const size_t MB = 1ull << 20;
  short* h      = (short*)(ws);
  short* q      = (short*)(ws + 16*MB);
  short* kmat   = (short*)(ws + 32*MB);
  short* vt     = (short*)(ws + 48*MB);
  short* ao     = (short*)(ws + 64*MB);
  short* wqb    = (short*)(ws + 80*MB);
  short* wkb    = wqb + 262144;
  short* wvb    = wkb + 262144;
  short* wob    = wvb + 262144;
  float* stats  = (float*)(ws + 82*MB);
  float* inv_den= (float*)(ws + 82*MB + 8192);
  float* partial= (float*)(ws + 83*MB);
  short* S      = (short*)(ws + 84*MB);

  const int LDS256 = 131072, LDS128 = 98304;
  hipFuncSetAttribute(reinterpret_cast<const void*>(&gemmF<4,256,1>),
                      hipFuncAttributeMaxDynamicSharedMemorySize, LDS256);
  hipFuncSetAttribute(reinterpret_cast<const void*>(&gemmF<4,256,0>),
                      hipFuncAttributeMaxDynamicSharedMemorySize, LDS256);
  hipFuncSetAttribute(reinterpret_cast<const void*>(&gemmF<0,128,0>),
                      hipFuncAttributeMaxDynamicSharedMemorySize, LDS128);
  hipFuncSetAttribute(reinterpret_cast<const void*>(&gemmF<1,128,0>),
                      hipFuncAttributeMaxDynamicSharedMemorySize, LDS128);
  hipFuncSetAttribute(reinterpret_cast<const void*>(&gemmF<2,128,0>),
                      hipFuncAttributeMaxDynamicSharedMemorySize, LDS128);
  hipFuncSetAttribute(reinterpret_cast<const void*>(&gemmF<5,128,2>),
                      hipFuncAttributeMaxDynamicSharedMemorySize, LDS128);
  hipFuncSetAttribute(reinterpret_cast<const void*>(&gemmF<5,128,0>),
                      hipFuncAttributeMaxDynamicSharedMemorySize, LDS128);

  dim3 blk(256);
  dim3 blk512(512);
  gn_stats<<<dim3(128), blk, 0, stream>>>(x, stats);
  gn_apply<<<dim3(64,4), blk, 0, stream>>>(x, stats, gnw, gnb, h);
  f2bf_all<<<dim3(512), blk, 0, stream>>>(Wq, Wk, Wv, Wo, wqb, wkb, wvb, wob);

  const long long sTok = 4096ll*512;
  const long long sS   = 4096ll*4096;
  const float qscale = 0.044194173824159216f;  // 1/sqrt(512)

  gemmF<0,128,0><<<dim3(16,4,4), blk512, LDS128, stream>>>(h, wqb, bq,  q,    nullptr, 4096, 512, 512, sTok, 0, sTok, qscale, nullptr, nullptr);
  gemmF<0,128,0><<<dim3(16,4,4), blk512, LDS128, stream>>>(h, wkb, bk,  kmat, nullptr, 4096, 512, 512, sTok, 0, sTok, 1.f, nullptr, nullptr);
  gemmF<1,128,0><<<dim3(16,4,4), blk512, LDS128, stream>>>(h, wvb, bvp, vt,   nullptr, 4096, 512, 512, sTok, 0, sTok, 1.f, nullptr, nullptr);

  if (ws_size >= 212*MB){
    gemmF<4,256,1><<<dim3(1024), blk512, LDS256, stream>>>(q, kmat, nullptr, S, nullptr, 4096, 4096, 512, sTok, sTok, sS, 1.f, nullptr, partial);
    reduce_den<<<dim3(64), blk, 0, stream>>>(partial, inv_den, 16384);
    gemmF<5,128,2><<<dim3(256), blk512, LDS128, stream>>>(S, vt, nullptr, ao, nullptr, 4096, 512, 4096, sS, sTok, sTok, 1.f, inv_den, nullptr);
  } else {
    for (int b = 0; b < 4; b++){
      gemmF<4,256,0><<<dim3(16,16,1), blk512, LDS256, stream>>>(q + b*sTok, kmat + b*sTok, nullptr, S, nullptr, 4096, 4096, 512, 0, 0, 0, 1.f, nullptr, partial);
      reduce_den<<<dim3(16), blk, 0, stream>>>(partial, inv_den, 4096);
      gemmF<5,128,0><<<dim3(16,4,1), blk512, LDS128, stream>>>(S, vt + b*sTok, nullptr, ao + b*sTok, nullptr, 4096, 512, 4096, 0, 0, 0, 1.f, inv_den, nullptr);
    }
  }

  gemmF<2,128,0><<<dim3(16,4,4), blk512, LDS128, stream>>>(ao, wob, bo, out, x, 4096, 512, 512, sTok, 0, sTok, 1.f, nullptr, nullptr);
}